// Round 4
// baseline (2054.088 us; speedup 1.0000x reference)
//
#include <hip/hip_runtime.h>
#include <stdint.h>

#define NA 200000
#define NB 300000
#define NG 10000
#define DD 256
#define EPS_GATE 1e-6f
#define EPS_BN 1e-5f

typedef short bf16x8 __attribute__((ext_vector_type(8)));
typedef float f32x4 __attribute__((ext_vector_type(4)));
typedef float f32x16 __attribute__((ext_vector_type(16)));

__device__ __forceinline__ unsigned short f2bf(float f){
  union { float f; uint32_t u; } v; v.f = f;
  uint32_t uu = v.u;
  uint32_t r = (uu + 0x7FFFu + ((uu >> 16) & 1u)) >> 16;
  return (unsigned short)r;
}
__device__ __forceinline__ float bf2f(unsigned short s){
  union { uint32_t u; float f; } v; v.u = ((uint32_t)s) << 16; return v.f;
}

// ---------------- zero fill ----------------
__global__ void k_zero(int4* p, size_t n16){
  for (size_t i = blockIdx.x*(size_t)blockDim.x + threadIdx.x; i < n16;
       i += (size_t)gridDim.x*blockDim.x)
    p[i] = make_int4(0,0,0,0);
}

// ---------------- W fp32 -> bf16 ----------------
__global__ void k_wconv(const float* __restrict__ W, unsigned short* __restrict__ Wbf, int n4){
  for (int i = blockIdx.x*blockDim.x + threadIdx.x; i < n4; i += gridDim.x*blockDim.x){
    float4 v = ((const float4*)W)[i];
    ushort4 o; o.x = f2bf(v.x); o.y = f2bf(v.y); o.z = f2bf(v.z); o.w = f2bf(v.w);
    ((ushort4*)Wbf)[i] = o;
  }
}

// ============ A-resident GEMM: Y[jj] = x @ W[j]^T + b[j], bf16 out ============
// Block 256 thr (4 waves), BM=64 rows, full K=256 of A staged swizzled in LDS
// (32 KB -> 4-5 blocks/CU). ONE barrier per block; B streamed from L2-resident W
// directly into registers. Wave w owns cols [64w, 64w+64): 2x2 mfma_32x32x16.
// A LDS swizzle: 16B granule g of row r stored at g' = g ^ ((r&15)<<1).
__global__ __launch_bounds__(256, 4) void k_gemm3(
    const float* __restrict__ x, int Nrows,
    const unsigned short* __restrict__ Wbf,
    const float* __restrict__ bias,
    unsigned short* __restrict__ Y,
    int j0, int j1, int j2, int j3, int nW)
{
  __shared__ unsigned short As[64*256];   // 32 KB
  const int tid  = threadIdx.x;
  const int wave = tid >> 6, lane = tid & 63;
  const int l31  = lane & 31, hi = lane >> 5;
  const int rowBase = blockIdx.x * 64;

  // ---- stage A: 64 rows x 256 cols fp32 -> bf16, swizzled granules ----
  #pragma unroll
  for (int i = 0; i < 8; ++i){
    int idx = i*256 + tid;            // granule index: row = idx>>5, g = idx&31
    int r = idx >> 5, g = idx & 31;
    f32x4 v0 = {0.f,0.f,0.f,0.f}, v1 = {0.f,0.f,0.f,0.f};
    if (rowBase + r < Nrows){
      const float* p = x + (size_t)(rowBase + r)*DD + g*8;
      v0 = *(const f32x4*)p; v1 = *(const f32x4*)(p + 4);
    }
    uint32_t d[4];
    const uint32_t* a  = (const uint32_t*)&v0;
    const uint32_t* b2 = (const uint32_t*)&v1;
    d[0] = __builtin_amdgcn_perm(a[1],  a[0],  0x07060302u);
    d[1] = __builtin_amdgcn_perm(a[3],  a[2],  0x07060302u);
    d[2] = __builtin_amdgcn_perm(b2[1], b2[0], 0x07060302u);
    d[3] = __builtin_amdgcn_perm(b2[3], b2[2], 0x07060302u);
    int gs = g ^ ((r & 15) << 1);
    *(int4*)(As + r*256 + gs*8) = *(int4*)d;
  }
  __syncthreads();   // the only barrier

  const int colW = wave*64;
  const int swz  = (l31 & 15) << 1;

  for (int jj = 0; jj < nW; ++jj){
    const int j = (jj==0) ? j0 : (jj==1) ? j1 : (jj==2) ? j2 : j3;
    const unsigned short* Wj = Wbf + (size_t)j*DD*DD;
    const float* bj = bias + (size_t)j*DD;
    unsigned short* Yj = Y + (size_t)jj*Nrows*DD;

    f32x16 acc00, acc01, acc10, acc11;
    #pragma unroll
    for (int r = 0; r < 16; ++r){ acc00[r]=0.f; acc01[r]=0.f; acc10[r]=0.f; acc11[r]=0.f; }

    #pragma unroll
    for (int ks = 0; ks < 16; ++ks){
      // B from global (L2-resident W): col = colW + n*32 + l31, k = ks*16 + hi*8 + e
      bf16x8 fB0 = *(const bf16x8*)(Wj + (size_t)(colW      + l31)*DD + ks*16 + hi*8);
      bf16x8 fB1 = *(const bf16x8*)(Wj + (size_t)(colW + 32 + l31)*DD + ks*16 + hi*8);
      // A from LDS: row = m*32 + l31 (swizzle term same for both m)
      int gp = (ks*2 + hi) ^ swz;
      bf16x8 fA0 = *(const bf16x8*)(As + l31*256        + gp*8);
      bf16x8 fA1 = *(const bf16x8*)(As + (32+l31)*256   + gp*8);
      acc00 = __builtin_amdgcn_mfma_f32_32x32x16_bf16(fA0, fB0, acc00, 0,0,0);
      acc01 = __builtin_amdgcn_mfma_f32_32x32x16_bf16(fA0, fB1, acc01, 0,0,0);
      acc10 = __builtin_amdgcn_mfma_f32_32x32x16_bf16(fA1, fB0, acc10, 0,0,0);
      acc11 = __builtin_amdgcn_mfma_f32_32x32x16_bf16(fA1, fB1, acc11, 0,0,0);
    }

    // epilogue: D col = l31 (+n*32), row = m*32 + 4*hi + (reg&3) + 8*(reg>>2)
    const float bv0 = bj[colW + l31];
    const float bv1 = bj[colW + 32 + l31];
    #pragma unroll
    for (int m = 0; m < 2; ++m){
      const f32x16& a0 = m ? acc10 : acc00;
      const f32x16& a1 = m ? acc11 : acc01;
      #pragma unroll
      for (int reg = 0; reg < 16; ++reg){
        int row = rowBase + m*32 + 4*hi + (reg & 3) + 8*(reg >> 2);
        if (row < Nrows){
          Yj[(size_t)row*DD + colW      + l31] = f2bf(a0[reg] + bv0);
          Yj[(size_t)row*DD + colW + 32 + l31] = f2bf(a1[reg] + bv1);
        }
      }
    }
  }
}

// ---------------- histograms ----------------
__global__ void k_hist(const int* __restrict__ ba, const int* __restrict__ b2g,
                       const int* __restrict__ a2g,
                       int* deg, int* cntb, int* cnta){
  int stride = gridDim.x*blockDim.x;
  for (int i = blockIdx.x*blockDim.x + threadIdx.x; i < NB; i += stride){
    atomicAdd(&deg[ba[2*i]],   1);
    atomicAdd(&deg[ba[2*i+1]], 1);
    atomicAdd(&cntb[b2g[i]],   1);
  }
  for (int i = blockIdx.x*blockDim.x + threadIdx.x; i < NA; i += stride)
    atomicAdd(&cnta[a2g[i]], 1);
}

// ---------------- exclusive scan (3-phase), 2048 elems/block ----------------
__global__ void k_scan_partials(const int* __restrict__ in, int n, int* __restrict__ part){
  __shared__ int sd[256];
  int base = blockIdx.x*2048;
  int s = 0;
  #pragma unroll
  for (int i=0;i<8;i++){
    int idx = base + threadIdx.x*8 + i;
    if (idx < n) s += in[idx];
  }
  sd[threadIdx.x] = s;
  __syncthreads();
  for (int off=128; off>0; off>>=1){
    if (threadIdx.x < off) sd[threadIdx.x] += sd[threadIdx.x+off];
    __syncthreads();
  }
  if (threadIdx.x==0) part[blockIdx.x] = sd[0];
}
__global__ void k_scan_small(int* part, int nb){
  if (threadIdx.x==0 && blockIdx.x==0){
    int run = 0;
    for (int i=0;i<nb;i++){ int v = part[i]; part[i] = run; run += v; }
    part[nb] = run;
  }
}
__global__ void k_scan_final(const int* __restrict__ in, int n,
                             const int* __restrict__ part, int* __restrict__ outp){
  __shared__ int sd[256];
  int base = blockIdx.x*2048;
  int loc[8];
  int s = 0;
  #pragma unroll
  for (int i=0;i<8;i++){
    int idx = base + threadIdx.x*8 + i;
    int v = (idx < n) ? in[idx] : 0;
    loc[i] = s; s += v;
  }
  sd[threadIdx.x] = s;
  __syncthreads();
  int mine = s;
  for (int off=1; off<256; off<<=1){
    int add = (threadIdx.x >= off) ? sd[threadIdx.x - off] : 0;
    __syncthreads();
    sd[threadIdx.x] += add;
    __syncthreads();
  }
  int b0 = part[blockIdx.x] + sd[threadIdx.x] - mine;
  #pragma unroll
  for (int i=0;i<8;i++){
    int idx = base + threadIdx.x*8 + i;
    if (idx < n) outp[idx] = b0 + loc[i];
  }
  if (blockIdx.x==0 && threadIdx.x==0) outp[n] = part[gridDim.x];
}

// ---------------- scatter: graph lists + bond-incidence lists ----------------
__global__ void k_scatter_atoms(const int* __restrict__ a2g, const int* __restrict__ goffa,
                                int* cura, int* alist){
  for (int i = blockIdx.x*blockDim.x + threadIdx.x; i < NA; i += gridDim.x*blockDim.x){
    int g = a2g[i];
    int p = atomicAdd(&cura[g], 1);
    alist[goffa[g] + p] = i;
  }
}
__global__ void k_scatter_bonds(const int* __restrict__ ba, const int* __restrict__ b2g,
                                const int* __restrict__ goffb, int* curb, int* blist,
                                const int* __restrict__ aoff, int* cur_atom,
                                int* incb, int* inco){
  for (int i = blockIdx.x*blockDim.x + threadIdx.x; i < NB; i += gridDim.x*blockDim.x){
    int g = b2g[i];
    int p = atomicAdd(&curb[g], 1);
    blist[goffb[g] + p] = i;
    int i0 = ba[2*i], i1 = ba[2*i+1];
    int q0 = atomicAdd(&cur_atom[i0], 1);
    incb[aoff[i0]+q0] = i; inco[aoff[i0]+q0] = i1;
    int q1 = atomicAdd(&cur_atom[i1], 1);
    incb[aoff[i1]+q1] = i; inco[aoff[i1]+q1] = i0;
  }
}

// ---------------- bond kernel: e_new, sigma, e_pre(=e_new*snorm_e), e-BN stats -----
__global__ __launch_bounds__(256) void k_bond(
    const unsigned short* __restrict__ Ah, const unsigned short* __restrict__ Be,
    const unsigned short* __restrict__ Cu,
    const int* __restrict__ ba, const int* __restrict__ b2g,
    const float* __restrict__ sne,
    unsigned short* __restrict__ Sg, float* __restrict__ e_pre,
    float* esum, float* esumsq)
{
  const int wave = threadIdx.x >> 6, lane = threadIdx.x & 63;
  float s1[4] = {0,0,0,0}, s2[4] = {0,0,0,0};
  const int wstride = gridDim.x*4;
  for (int bond = blockIdx.x*4 + wave; bond < NB; bond += wstride){
    int i0 = ba[2*bond], i1 = ba[2*bond+1];
    int g  = b2g[bond];
    float sn = sne[bond];
    ushort4 a0 = *(const ushort4*)(Ah + (size_t)i0*DD + lane*4);
    ushort4 a1 = *(const ushort4*)(Ah + (size_t)i1*DD + lane*4);
    ushort4 be = *(const ushort4*)(Be + (size_t)bond*DD + lane*4);
    ushort4 cu = *(const ushort4*)(Cu + (size_t)g*DD + lane*4);
    float e0 = bf2f(a0.x)+bf2f(a1.x)+bf2f(be.x)+bf2f(cu.x);
    float e1 = bf2f(a0.y)+bf2f(a1.y)+bf2f(be.y)+bf2f(cu.y);
    float e2 = bf2f(a0.z)+bf2f(a1.z)+bf2f(be.z)+bf2f(cu.z);
    float e3 = bf2f(a0.w)+bf2f(a1.w)+bf2f(be.w)+bf2f(cu.w);
    ushort4 sg;
    sg.x = f2bf(1.f/(1.f+__expf(-e0)));
    sg.y = f2bf(1.f/(1.f+__expf(-e1)));
    sg.z = f2bf(1.f/(1.f+__expf(-e2)));
    sg.w = f2bf(1.f/(1.f+__expf(-e3)));
    *(ushort4*)(Sg + (size_t)bond*DD + lane*4) = sg;
    float4 ep; ep.x = e0*sn; ep.y = e1*sn; ep.z = e2*sn; ep.w = e3*sn;
    *(float4*)(e_pre + (size_t)bond*DD + lane*4) = ep;
    s1[0]+=ep.x; s2[0]+=ep.x*ep.x;
    s1[1]+=ep.y; s2[1]+=ep.y*ep.y;
    s1[2]+=ep.z; s2[2]+=ep.z*ep.z;
    s1[3]+=ep.w; s2[3]+=ep.w*ep.w;
  }
  __shared__ float red[4*DD];
  #pragma unroll
  for (int c=0;c<4;c++) red[wave*DD + lane*4 + c] = s1[c];
  __syncthreads();
  if (threadIdx.x < DD){
    float t = red[threadIdx.x] + red[DD+threadIdx.x] + red[2*DD+threadIdx.x] + red[3*DD+threadIdx.x];
    atomicAdd(&esum[threadIdx.x], t);
  }
  __syncthreads();
  #pragma unroll
  for (int c=0;c<4;c++) red[wave*DD + lane*4 + c] = s2[c];
  __syncthreads();
  if (threadIdx.x < DD){
    float t = red[threadIdx.x] + red[DD+threadIdx.x] + red[2*DD+threadIdx.x] + red[3*DD+threadIdx.x];
    atomicAdd(&esumsq[threadIdx.x], t);
  }
}

// ---------------- atom kernel: gate via incidence CSR, h_pre, h-BN stats -----------
__global__ __launch_bounds__(256) void k_atom(
    const unsigned short* __restrict__ Dh, const unsigned short* __restrict__ Eh,
    const unsigned short* __restrict__ Fu, const unsigned short* __restrict__ Sg,
    const int* __restrict__ aoff, const int* __restrict__ incb, const int* __restrict__ inco,
    const int* __restrict__ a2g, const float* __restrict__ snn,
    float* __restrict__ h_pre, float* hsum, float* hsumsq)
{
  const int wave = threadIdx.x >> 6, lane = threadIdx.x & 63;
  float s1[4] = {0,0,0,0}, s2[4] = {0,0,0,0};
  const int wstride = gridDim.x*4;
  for (int a = blockIdx.x*4 + wave; a < NA; a += wstride){
    int j0 = aoff[a], j1 = aoff[a+1];
    float num[4] = {0,0,0,0}, den[4] = {0,0,0,0};
    for (int j = j0; j < j1; ++j){
      int bond = incb[j], other = inco[j];
      ushort4 sg = *(const ushort4*)(Sg + (size_t)bond*DD + lane*4);
      ushort4 eo = *(const ushort4*)(Eh + (size_t)other*DD + lane*4);
      float g0 = bf2f(sg.x), g1 = bf2f(sg.y), g2 = bf2f(sg.z), g3 = bf2f(sg.w);
      num[0] += g0*bf2f(eo.x); num[1] += g1*bf2f(eo.y);
      num[2] += g2*bf2f(eo.z); num[3] += g3*bf2f(eo.w);
      den[0] += g0; den[1] += g1; den[2] += g2; den[3] += g3;
    }
    int g = a2g[a]; float sn = snn[a];
    ushort4 dh = *(const ushort4*)(Dh + (size_t)a*DD + lane*4);
    ushort4 fu = *(const ushort4*)(Fu + (size_t)g*DD + lane*4);
    float4 hv;
    hv.x = (bf2f(dh.x) + num[0]/(den[0]+EPS_GATE) + bf2f(fu.x))*sn;
    hv.y = (bf2f(dh.y) + num[1]/(den[1]+EPS_GATE) + bf2f(fu.y))*sn;
    hv.z = (bf2f(dh.z) + num[2]/(den[2]+EPS_GATE) + bf2f(fu.z))*sn;
    hv.w = (bf2f(dh.w) + num[3]/(den[3]+EPS_GATE) + bf2f(fu.w))*sn;
    *(float4*)(h_pre + (size_t)a*DD + lane*4) = hv;
    s1[0]+=hv.x; s2[0]+=hv.x*hv.x;
    s1[1]+=hv.y; s2[1]+=hv.y*hv.y;
    s1[2]+=hv.z; s2[2]+=hv.z*hv.z;
    s1[3]+=hv.w; s2[3]+=hv.w*hv.w;
  }
  __shared__ float red[4*DD];
  #pragma unroll
  for (int c=0;c<4;c++) red[wave*DD + lane*4 + c] = s1[c];
  __syncthreads();
  if (threadIdx.x < DD){
    float t = red[threadIdx.x] + red[DD+threadIdx.x] + red[2*DD+threadIdx.x] + red[3*DD+threadIdx.x];
    atomicAdd(&hsum[threadIdx.x], t);
  }
  __syncthreads();
  #pragma unroll
  for (int c=0;c<4;c++) red[wave*DD + lane*4 + c] = s2[c];
  __syncthreads();
  if (threadIdx.x < DD){
    float t = red[threadIdx.x] + red[DD+threadIdx.x] + red[2*DD+threadIdx.x] + red[3*DD+threadIdx.x];
    atomicAdd(&hsumsq[threadIdx.x], t);
  }
}

// ---------------- graph kernel: u_pre per graph (block per graph) ------------------
__global__ __launch_bounds__(256) void k_graph(
    const unsigned short* __restrict__ Gh, const unsigned short* __restrict__ He,
    const unsigned short* __restrict__ Iu,
    const int* __restrict__ goffa, const int* __restrict__ alist,
    const int* __restrict__ goffb, const int* __restrict__ blist,
    float* __restrict__ u_pre)
{
  int g = blockIdx.x, t = threadIdx.x;
  int a0 = goffa[g], a1 = goffa[g+1];
  float sA = 0.f;
  for (int i = a0; i < a1; ++i) sA += bf2f(Gh[(size_t)alist[i]*DD + t]);
  int b0 = goffb[g], b1 = goffb[g+1];
  float sB = 0.f;
  for (int i = b0; i < b1; ++i) sB += bf2f(He[(size_t)blist[i]*DD + t]);
  float cA = (float)max(a1 - a0, 1);
  float cB = (float)max(b1 - b0, 1);
  u_pre[(size_t)g*DD + t] = sA/cA + sB/cB + bf2f(Iu[(size_t)g*DD + t]);
}

__global__ void k_ustats(const float* __restrict__ u_pre, float* usum, float* usumsq){
  int t = threadIdx.x;
  float s = 0.f, s2 = 0.f;
  for (int g = blockIdx.x; g < NG; g += gridDim.x){
    float v = u_pre[(size_t)g*DD + t];
    s += v; s2 += v*v;
  }
  atomicAdd(&usum[t], s);
  atomicAdd(&usumsq[t], s2);
}

// ---------------- BN finalize + normalize/ELU ----------------
__global__ void k_bnfin(const float* __restrict__ sums, const float* __restrict__ sumsq,
                        float* __restrict__ mr){
  int o = blockIdx.x, t = threadIdx.x;
  float n = (o==0) ? (float)NA : (o==1) ? (float)NB : (float)NG;
  float m = sums[o*DD+t]/n;
  float v = sumsq[o*DD+t]/n - m*m;
  mr[o*2*DD + t]      = m;
  mr[o*2*DD + DD + t] = rsqrtf(fmaxf(v, 0.f) + EPS_BN);
}

__global__ __launch_bounds__(256) void k_norm(
    float* __restrict__ buf, size_t nrows,
    const float* __restrict__ mr, const float* __restrict__ gamma,
    const float* __restrict__ beta)
{
  __shared__ float sm[DD], sr[DD], sg[DD], sb[DD];
  int t = threadIdx.x;
  sm[t] = mr[t]; sr[t] = mr[DD+t]; sg[t] = gamma[t]; sb[t] = beta[t];
  __syncthreads();
  size_t total = nrows*(DD/4);
  for (size_t i = blockIdx.x*(size_t)blockDim.x + t; i < total;
       i += (size_t)gridDim.x*blockDim.x){
    int c = ((int)(i & 63))*4;
    float4 v = ((float4*)buf)[i];
    float z0 = (v.x - sm[c+0])*sr[c+0]*sg[c+0] + sb[c+0];
    float z1 = (v.y - sm[c+1])*sr[c+1]*sg[c+1] + sb[c+1];
    float z2 = (v.z - sm[c+2])*sr[c+2]*sg[c+2] + sb[c+2];
    float z3 = (v.w - sm[c+3])*sr[c+3]*sg[c+3] + sb[c+3];
    v.x = z0 > 0.f ? z0 : expm1f(z0);
    v.y = z1 > 0.f ? z1 : expm1f(z1);
    v.z = z2 > 0.f ? z2 : expm1f(z2);
    v.w = z3 > 0.f ? z3 : expm1f(z3);
    ((float4*)buf)[i] = v;
  }
}

// ================================ launcher =================================
extern "C" void kernel_launch(void* const* d_in, const int* in_sizes, int n_in,
                              void* d_out, int out_size, void* d_ws, size_t ws_size,
                              hipStream_t stream)
{
  (void)in_sizes; (void)n_in; (void)out_size;
  const float* h   = (const float*)d_in[0];
  const float* e   = (const float*)d_in[1];
  const float* u   = (const float*)d_in[2];
  const float* snn = (const float*)d_in[3];
  const float* sne = (const float*)d_in[4];
  const float* W   = (const float*)d_in[5];
  const float* b   = (const float*)d_in[6];
  const float* gamma = (const float*)d_in[7];
  const float* beta  = (const float*)d_in[8];
  const int* ba  = (const int*)d_in[9];
  const int* a2g = (const int*)d_in[10];
  const int* b2g = (const int*)d_in[11];

  float* outp  = (float*)d_out;
  float* h_pre = outp;
  float* e_pre = outp + (size_t)NA*DD;
  float* u_pre = outp + (size_t)(NA+NB)*DD;

  char* ws = (char*)d_ws;
  size_t off = 0;
  auto alloc = [&](size_t bytes)->char* {
    char* p = ws + off;
    off += (bytes + 255) & ~(size_t)255;
    return p;
  };
  unsigned short* Wbf = (unsigned short*)alloc((size_t)9*DD*DD*2);
  unsigned short* Yh  = (unsigned short*)alloc((size_t)4*NA*DD*2);
  unsigned short* Ye  = (unsigned short*)alloc((size_t)2*NB*DD*2);
  unsigned short* Yu  = (unsigned short*)alloc((size_t)3*NG*DD*2);
  unsigned short* Sg  = (unsigned short*)alloc((size_t)NB*DD*2);
  int* aoff  = (int*)alloc((size_t)(NA+1)*4);
  int* goffa = (int*)alloc((size_t)(NG+1)*4);
  int* goffb = (int*)alloc((size_t)(NG+1)*4);
  int* alist = (int*)alloc((size_t)NA*4);
  int* blist = (int*)alloc((size_t)NB*4);
  int* incb  = (int*)alloc((size_t)2*NB*4);
  int* inco  = (int*)alloc((size_t)2*NB*4);
  int* part  = (int*)alloc(1024);
  float* mr  = (float*)alloc((size_t)3*2*DD*4);
  char* zz   = ws + off;                      // ---- zero zone start ----
  int* deg      = (int*)alloc((size_t)NA*4);
  int* cur_atom = (int*)alloc((size_t)NA*4);
  int* cnta  = (int*)alloc((size_t)NG*4);
  int* cntb  = (int*)alloc((size_t)NG*4);
  int* cura  = (int*)alloc((size_t)NG*4);
  int* curb  = (int*)alloc((size_t)NG*4);
  float* sums  = (float*)alloc((size_t)3*DD*4);
  float* sumsq = (float*)alloc((size_t)3*DD*4);
  size_t zbytes = (size_t)((ws + off) - zz);

  if (ws_size < off) return;

  unsigned short* Ah = Yh;
  unsigned short* Dh = Yh + (size_t)1*NA*DD;
  unsigned short* Eh = Yh + (size_t)2*NA*DD;
  unsigned short* Gh = Yh + (size_t)3*NA*DD;
  unsigned short* Be = Ye;
  unsigned short* He = Ye + (size_t)NB*DD;
  unsigned short* Cu = Yu;
  unsigned short* Fu = Yu + (size_t)1*NG*DD;
  unsigned short* Iu = Yu + (size_t)2*NG*DD;

  k_zero<<<256, 256, 0, stream>>>((int4*)zz, zbytes/16);
  k_wconv<<<288, 256, 0, stream>>>(W, Wbf, 9*DD*DD/4);

  k_gemm3<<<(NA+63)/64, 256, 0, stream>>>(h, NA, Wbf, b, Yh, 0,3,4,6, 4);
  k_gemm3<<<(NB+63)/64, 256, 0, stream>>>(e, NB, Wbf, b, Ye, 1,7,0,0, 2);
  k_gemm3<<<(NG+63)/64, 256, 0, stream>>>(u, NG, Wbf, b, Yu, 2,5,8,0, 3);

  k_hist<<<1024, 256, 0, stream>>>(ba, b2g, a2g, deg, cntb, cnta);

  k_scan_partials<<<98, 256, 0, stream>>>(deg, NA, part);
  k_scan_small<<<1, 64, 0, stream>>>(part, 98);
  k_scan_final<<<98, 256, 0, stream>>>(deg, NA, part, aoff);
  k_scan_partials<<<5, 256, 0, stream>>>(cnta, NG, part);
  k_scan_small<<<1, 64, 0, stream>>>(part, 5);
  k_scan_final<<<5, 256, 0, stream>>>(cnta, NG, part, goffa);
  k_scan_partials<<<5, 256, 0, stream>>>(cntb, NG, part);
  k_scan_small<<<1, 64, 0, stream>>>(part, 5);
  k_scan_final<<<5, 256, 0, stream>>>(cntb, NG, part, goffb);

  k_scatter_atoms<<<512, 256, 0, stream>>>(a2g, goffa, cura, alist);
  k_scatter_bonds<<<512, 256, 0, stream>>>(ba, b2g, goffb, curb, blist,
                                           aoff, cur_atom, incb, inco);

  k_bond<<<2048, 256, 0, stream>>>(Ah, Be, Cu, ba, b2g, sne, Sg, e_pre,
                                   sums + DD, sumsq + DD);
  k_atom<<<2048, 256, 0, stream>>>(Dh, Eh, Fu, Sg, aoff, incb, inco, a2g, snn,
                                   h_pre, sums + 0, sumsq + 0);
  k_graph<<<NG, 256, 0, stream>>>(Gh, He, Iu, goffa, alist, goffb, blist, u_pre);
  k_ustats<<<40, 256, 0, stream>>>(u_pre, sums + 2*DD, sumsq + 2*DD);

  k_bnfin<<<3, 256, 0, stream>>>(sums, sumsq, mr);

  k_norm<<<2048, 256, 0, stream>>>(h_pre, (size_t)NA, mr + 0,      gamma + 0,    beta + 0);
  k_norm<<<2048, 256, 0, stream>>>(e_pre, (size_t)NB, mr + 2*DD,   gamma + DD,   beta + DD);
  k_norm<<<64,   256, 0, stream>>>(u_pre, (size_t)NG, mr + 4*DD,   gamma + 2*DD, beta + 2*DD);
}

// Round 5
// 1604.755 us; speedup vs baseline: 1.2800x; 1.2800x over previous
//
#include <hip/hip_runtime.h>
#include <stdint.h>

#define NA 200000
#define NB 300000
#define NG 10000
#define DD 256
#define EPS_GATE 1e-6f
#define EPS_BN 1e-5f

typedef short bf16x8 __attribute__((ext_vector_type(8)));
typedef float f32x4 __attribute__((ext_vector_type(4)));

__device__ __forceinline__ unsigned short f2bf(float f){
  union { float f; uint32_t u; } v; v.f = f;
  uint32_t uu = v.u;
  uint32_t r = (uu + 0x7FFFu + ((uu >> 16) & 1u)) >> 16;
  return (unsigned short)r;
}
__device__ __forceinline__ float bf2f(unsigned short s){
  union { uint32_t u; float f; } v; v.u = ((uint32_t)s) << 16; return v.f;
}

__device__ __forceinline__ void gload_lds16(const unsigned short* g, unsigned short* l){
  __builtin_amdgcn_global_load_lds(
      (const __attribute__((address_space(1))) unsigned int*)g,
      (__attribute__((address_space(3))) unsigned int*)l, 16, 0, 0);
}

// ---------------- zero fill ----------------
__global__ void k_zero(int4* p, size_t n16){
  for (size_t i = blockIdx.x*(size_t)blockDim.x + threadIdx.x; i < n16;
       i += (size_t)gridDim.x*blockDim.x)
    p[i] = make_int4(0,0,0,0);
}

// ---------------- W fp32 -> bf16 ----------------
__global__ void k_wconv(const float* __restrict__ W, unsigned short* __restrict__ Wbf, int n4){
  for (int i = blockIdx.x*blockDim.x + threadIdx.x; i < n4; i += gridDim.x*blockDim.x){
    float4 v = ((const float4*)W)[i];
    ushort4 o; o.x = f2bf(v.x); o.y = f2bf(v.y); o.z = f2bf(v.z); o.w = f2bf(v.w);
    ((ushort4*)Wbf)[i] = o;
  }
}

// ============ m97-style fused GEMM: Y[jj] = x @ W[j]^T + b[j], bf16 out ============
// 512 thr (8 waves: wr=wave>>2 in {0,1} M-half, wc=wave&3 N-quarter).
// Tile: 128 rows x 256 cols. A (full K=256) staged ONCE as swizzled bf16 (64KB).
// B: one 256x32 slice (16KB) per K-step via global_load_lds (inverse-swizzled src).
// LDS = 80KB -> 2 blocks/CU. mfma_16x16x32, wave = 4x4 frags (64x64 out).
// A swizzle: granule g of row r at g^((r&15)<<1). B: slot s of row n at s^((n>>1)&3).
__global__ __launch_bounds__(512, 4) void k_gemm4(
    const float* __restrict__ x, int Nrows,
    const unsigned short* __restrict__ Wbf,
    const float* __restrict__ bias,
    unsigned short* __restrict__ Y,
    int j0, int j1, int j2, int j3, int nW)
{
  __shared__ unsigned short As[128*256];   // 64 KB
  __shared__ unsigned short Bs[256*32];    // 16 KB
  const int tid  = threadIdx.x;
  const int wave = tid >> 6, lane = tid & 63;
  const int l15  = lane & 15, kq = lane >> 4;
  const int wr   = wave >> 2, wc = wave & 3;
  const int rowBase = blockIdx.x * 128;

  // ---- stage A: 128 rows x 256 cols fp32 -> bf16, swizzled granules ----
  #pragma unroll
  for (int i = 0; i < 8; ++i){
    int idx = i*512 + tid;           // granule index: row = idx>>5, g = idx&31
    int r = idx >> 5, g = idx & 31;
    f32x4 v0 = {0.f,0.f,0.f,0.f}, v1 = {0.f,0.f,0.f,0.f};
    if (rowBase + r < Nrows){
      const float* p = x + (size_t)(rowBase + r)*DD + g*8;
      v0 = *(const f32x4*)p; v1 = *(const f32x4*)(p + 4);
    }
    uint32_t d[4];
    const uint32_t* a  = (const uint32_t*)&v0;
    const uint32_t* b2 = (const uint32_t*)&v1;
    d[0] = __builtin_amdgcn_perm(a[1],  a[0],  0x07060302u);
    d[1] = __builtin_amdgcn_perm(a[3],  a[2],  0x07060302u);
    d[2] = __builtin_amdgcn_perm(b2[1], b2[0], 0x07060302u);
    d[3] = __builtin_amdgcn_perm(b2[3], b2[2], 0x07060302u);
    int gs = g ^ ((r & 15) << 1);
    *(int4*)(As + r*256 + gs*8) = *(int4*)d;
  }

  const int sB = kq ^ ((l15 >> 1) & 3);    // B LDS read slot (row>>1 term = (l15>>1)&3)

  for (int jj = 0; jj < nW; ++jj){
    const int j = (jj==0) ? j0 : (jj==1) ? j1 : (jj==2) ? j2 : j3;
    const unsigned short* Wj = Wbf + (size_t)j*DD*DD;
    const float* bj = bias + (size_t)j*DD;
    unsigned short* Yj = Y + (size_t)jj*Nrows*DD;

    f32x4 acc[4][4];
    #pragma unroll
    for (int m=0;m<4;m++)
      #pragma unroll
      for (int n=0;n<4;n++)
        acc[m][n] = (f32x4){0.f,0.f,0.f,0.f};

    for (int ks = 0; ks < 8; ++ks){
      __syncthreads();   // all waves done reading Bs (and, first time, As written)
      // stage B slice [256 rows(N) x 32 K] with inverse-swizzled source
      #pragma unroll
      for (int i = 0; i < 2; ++i){
        int idx  = i*512 + tid;        // granule: row = idx>>2, stored slot = idx&3
        int row  = idx >> 2;
        int slot = idx & 3;
        int srcg = slot ^ ((row >> 1) & 3);
        gload_lds16(Wj + (size_t)row*DD + ks*32 + srcg*8,
                    Bs + ((size_t)i*512 + wave*64)*8);
      }
      __syncthreads();   // drains gload_lds (vmcnt) + barrier

      bf16x8 afr[4], bfr[4];
      #pragma unroll
      for (int m=0;m<4;m++){
        int row = wr*64 + 16*m + l15;
        int gs = (ks*4 + kq) ^ (l15 << 1);
        afr[m] = *(const bf16x8*)(As + row*256 + gs*8);
      }
      #pragma unroll
      for (int n=0;n<4;n++){
        int row = wc*64 + 16*n + l15;
        bfr[n] = *(const bf16x8*)(Bs + row*32 + sB*8);
      }
      #pragma unroll
      for (int m=0;m<4;m++)
        #pragma unroll
        for (int n=0;n<4;n++)
          acc[m][n] = __builtin_amdgcn_mfma_f32_16x16x32_bf16(afr[m], bfr[n], acc[m][n], 0,0,0);
    }

    // epilogue: D row = wr*64 + 16m + 4*kq + r, col = wc*64 + 16n + l15
    #pragma unroll
    for (int m=0;m<4;m++){
      int row0 = rowBase + wr*64 + 16*m + 4*kq;
      #pragma unroll
      for (int n=0;n<4;n++){
        int col = wc*64 + 16*n + l15;
        float bv = bj[col];
        #pragma unroll
        for (int r=0;r<4;r++){
          int row = row0 + r;
          if (row < Nrows) Yj[(size_t)row*DD + col] = f2bf(acc[m][n][r] + bv);
        }
      }
    }
  }
}

// ---------------- histograms ----------------
__global__ void k_hist(const int* __restrict__ ba, const int* __restrict__ b2g,
                       const int* __restrict__ a2g,
                       int* deg, int* cntb, int* cnta){
  int stride = gridDim.x*blockDim.x;
  for (int i = blockIdx.x*blockDim.x + threadIdx.x; i < NB; i += stride){
    atomicAdd(&deg[ba[2*i]],   1);
    atomicAdd(&deg[ba[2*i+1]], 1);
    atomicAdd(&cntb[b2g[i]],   1);
  }
  for (int i = blockIdx.x*blockDim.x + threadIdx.x; i < NA; i += stride)
    atomicAdd(&cnta[a2g[i]], 1);
}

// ---------------- exclusive scan (3-phase), 2048 elems/block ----------------
__global__ void k_scan_partials(const int* __restrict__ in, int n, int* __restrict__ part){
  __shared__ int sd[256];
  int base = blockIdx.x*2048;
  int s = 0;
  #pragma unroll
  for (int i=0;i<8;i++){
    int idx = base + threadIdx.x*8 + i;
    if (idx < n) s += in[idx];
  }
  sd[threadIdx.x] = s;
  __syncthreads();
  for (int off=128; off>0; off>>=1){
    if (threadIdx.x < off) sd[threadIdx.x] += sd[threadIdx.x+off];
    __syncthreads();
  }
  if (threadIdx.x==0) part[blockIdx.x] = sd[0];
}
__global__ void k_scan_small(int* part, int nb){
  if (threadIdx.x==0 && blockIdx.x==0){
    int run = 0;
    for (int i=0;i<nb;i++){ int v = part[i]; part[i] = run; run += v; }
    part[nb] = run;
  }
}
__global__ void k_scan_final(const int* __restrict__ in, int n,
                             const int* __restrict__ part, int* __restrict__ outp){
  __shared__ int sd[256];
  int base = blockIdx.x*2048;
  int loc[8];
  int s = 0;
  #pragma unroll
  for (int i=0;i<8;i++){
    int idx = base + threadIdx.x*8 + i;
    int v = (idx < n) ? in[idx] : 0;
    loc[i] = s; s += v;
  }
  sd[threadIdx.x] = s;
  __syncthreads();
  int mine = s;
  for (int off=1; off<256; off<<=1){
    int add = (threadIdx.x >= off) ? sd[threadIdx.x - off] : 0;
    __syncthreads();
    sd[threadIdx.x] += add;
    __syncthreads();
  }
  int b0 = part[blockIdx.x] + sd[threadIdx.x] - mine;
  #pragma unroll
  for (int i=0;i<8;i++){
    int idx = base + threadIdx.x*8 + i;
    if (idx < n) outp[idx] = b0 + loc[i];
  }
  if (blockIdx.x==0 && threadIdx.x==0) outp[n] = part[gridDim.x];
}

// ---------------- scatter: graph lists + bond-incidence lists ----------------
__global__ void k_scatter_atoms(const int* __restrict__ a2g, const int* __restrict__ goffa,
                                int* cura, int* alist){
  for (int i = blockIdx.x*blockDim.x + threadIdx.x; i < NA; i += gridDim.x*blockDim.x){
    int g = a2g[i];
    int p = atomicAdd(&cura[g], 1);
    alist[goffa[g] + p] = i;
  }
}
__global__ void k_scatter_bonds(const int* __restrict__ ba, const int* __restrict__ b2g,
                                const int* __restrict__ goffb, int* curb, int* blist,
                                const int* __restrict__ aoff, int* cur_atom,
                                int* incb, int* inco){
  for (int i = blockIdx.x*blockDim.x + threadIdx.x; i < NB; i += gridDim.x*blockDim.x){
    int g = b2g[i];
    int p = atomicAdd(&curb[g], 1);
    blist[goffb[g] + p] = i;
    int i0 = ba[2*i], i1 = ba[2*i+1];
    int q0 = atomicAdd(&cur_atom[i0], 1);
    incb[aoff[i0]+q0] = i; inco[aoff[i0]+q0] = i1;
    int q1 = atomicAdd(&cur_atom[i1], 1);
    incb[aoff[i1]+q1] = i; inco[aoff[i1]+q1] = i0;
  }
}

// ---------------- bond kernel: e_new, sigma, e_pre(=e_new*snorm_e), e-BN stats -----
__global__ __launch_bounds__(256) void k_bond(
    const unsigned short* __restrict__ Ah, const unsigned short* __restrict__ Be,
    const unsigned short* __restrict__ Cu,
    const int* __restrict__ ba, const int* __restrict__ b2g,
    const float* __restrict__ sne,
    unsigned short* __restrict__ Sg, float* __restrict__ e_pre,
    float* esum, float* esumsq)
{
  const int wave = threadIdx.x >> 6, lane = threadIdx.x & 63;
  float s1[4] = {0,0,0,0}, s2[4] = {0,0,0,0};
  const int wstride = gridDim.x*4;
  for (int bond = blockIdx.x*4 + wave; bond < NB; bond += wstride){
    int i0 = ba[2*bond], i1 = ba[2*bond+1];
    int g  = b2g[bond];
    float sn = sne[bond];
    ushort4 a0 = *(const ushort4*)(Ah + (size_t)i0*DD + lane*4);
    ushort4 a1 = *(const ushort4*)(Ah + (size_t)i1*DD + lane*4);
    ushort4 be = *(const ushort4*)(Be + (size_t)bond*DD + lane*4);
    ushort4 cu = *(const ushort4*)(Cu + (size_t)g*DD + lane*4);
    float e0 = bf2f(a0.x)+bf2f(a1.x)+bf2f(be.x)+bf2f(cu.x);
    float e1 = bf2f(a0.y)+bf2f(a1.y)+bf2f(be.y)+bf2f(cu.y);
    float e2 = bf2f(a0.z)+bf2f(a1.z)+bf2f(be.z)+bf2f(cu.z);
    float e3 = bf2f(a0.w)+bf2f(a1.w)+bf2f(be.w)+bf2f(cu.w);
    ushort4 sg;
    sg.x = f2bf(1.f/(1.f+__expf(-e0)));
    sg.y = f2bf(1.f/(1.f+__expf(-e1)));
    sg.z = f2bf(1.f/(1.f+__expf(-e2)));
    sg.w = f2bf(1.f/(1.f+__expf(-e3)));
    *(ushort4*)(Sg + (size_t)bond*DD + lane*4) = sg;
    float4 ep; ep.x = e0*sn; ep.y = e1*sn; ep.z = e2*sn; ep.w = e3*sn;
    *(float4*)(e_pre + (size_t)bond*DD + lane*4) = ep;
    s1[0]+=ep.x; s2[0]+=ep.x*ep.x;
    s1[1]+=ep.y; s2[1]+=ep.y*ep.y;
    s1[2]+=ep.z; s2[2]+=ep.z*ep.z;
    s1[3]+=ep.w; s2[3]+=ep.w*ep.w;
  }
  __shared__ float red[4*DD];
  #pragma unroll
  for (int c=0;c<4;c++) red[wave*DD + lane*4 + c] = s1[c];
  __syncthreads();
  if (threadIdx.x < DD){
    float t = red[threadIdx.x] + red[DD+threadIdx.x] + red[2*DD+threadIdx.x] + red[3*DD+threadIdx.x];
    atomicAdd(&esum[threadIdx.x], t);
  }
  __syncthreads();
  #pragma unroll
  for (int c=0;c<4;c++) red[wave*DD + lane*4 + c] = s2[c];
  __syncthreads();
  if (threadIdx.x < DD){
    float t = red[threadIdx.x] + red[DD+threadIdx.x] + red[2*DD+threadIdx.x] + red[3*DD+threadIdx.x];
    atomicAdd(&esumsq[threadIdx.x], t);
  }
}

// ---------------- atom kernel: gate via incidence CSR, h_pre, h-BN stats -----------
__global__ __launch_bounds__(256) void k_atom(
    const unsigned short* __restrict__ Dh, const unsigned short* __restrict__ Eh,
    const unsigned short* __restrict__ Fu, const unsigned short* __restrict__ Sg,
    const int* __restrict__ aoff, const int* __restrict__ incb, const int* __restrict__ inco,
    const int* __restrict__ a2g, const float* __restrict__ snn,
    float* __restrict__ h_pre, float* hsum, float* hsumsq)
{
  const int wave = threadIdx.x >> 6, lane = threadIdx.x & 63;
  float s1[4] = {0,0,0,0}, s2[4] = {0,0,0,0};
  const int wstride = gridDim.x*4;
  for (int a = blockIdx.x*4 + wave; a < NA; a += wstride){
    int j0 = aoff[a], j1 = aoff[a+1];
    float num[4] = {0,0,0,0}, den[4] = {0,0,0,0};
    for (int j = j0; j < j1; ++j){
      int bond = incb[j], other = inco[j];
      ushort4 sg = *(const ushort4*)(Sg + (size_t)bond*DD + lane*4);
      ushort4 eo = *(const ushort4*)(Eh + (size_t)other*DD + lane*4);
      float g0 = bf2f(sg.x), g1 = bf2f(sg.y), g2 = bf2f(sg.z), g3 = bf2f(sg.w);
      num[0] += g0*bf2f(eo.x); num[1] += g1*bf2f(eo.y);
      num[2] += g2*bf2f(eo.z); num[3] += g3*bf2f(eo.w);
      den[0] += g0; den[1] += g1; den[2] += g2; den[3] += g3;
    }
    int g = a2g[a]; float sn = snn[a];
    ushort4 dh = *(const ushort4*)(Dh + (size_t)a*DD + lane*4);
    ushort4 fu = *(const ushort4*)(Fu + (size_t)g*DD + lane*4);
    float4 hv;
    hv.x = (bf2f(dh.x) + num[0]/(den[0]+EPS_GATE) + bf2f(fu.x))*sn;
    hv.y = (bf2f(dh.y) + num[1]/(den[1]+EPS_GATE) + bf2f(fu.y))*sn;
    hv.z = (bf2f(dh.z) + num[2]/(den[2]+EPS_GATE) + bf2f(fu.z))*sn;
    hv.w = (bf2f(dh.w) + num[3]/(den[3]+EPS_GATE) + bf2f(fu.w))*sn;
    *(float4*)(h_pre + (size_t)a*DD + lane*4) = hv;
    s1[0]+=hv.x; s2[0]+=hv.x*hv.x;
    s1[1]+=hv.y; s2[1]+=hv.y*hv.y;
    s1[2]+=hv.z; s2[2]+=hv.z*hv.z;
    s1[3]+=hv.w; s2[3]+=hv.w*hv.w;
  }
  __shared__ float red[4*DD];
  #pragma unroll
  for (int c=0;c<4;c++) red[wave*DD + lane*4 + c] = s1[c];
  __syncthreads();
  if (threadIdx.x < DD){
    float t = red[threadIdx.x] + red[DD+threadIdx.x] + red[2*DD+threadIdx.x] + red[3*DD+threadIdx.x];
    atomicAdd(&hsum[threadIdx.x], t);
  }
  __syncthreads();
  #pragma unroll
  for (int c=0;c<4;c++) red[wave*DD + lane*4 + c] = s2[c];
  __syncthreads();
  if (threadIdx.x < DD){
    float t = red[threadIdx.x] + red[DD+threadIdx.x] + red[2*DD+threadIdx.x] + red[3*DD+threadIdx.x];
    atomicAdd(&hsumsq[threadIdx.x], t);
  }
}

// ---------------- graph kernel: u_pre per graph (block per graph) ------------------
__global__ __launch_bounds__(256) void k_graph(
    const unsigned short* __restrict__ Gh, const unsigned short* __restrict__ He,
    const unsigned short* __restrict__ Iu,
    const int* __restrict__ goffa, const int* __restrict__ alist,
    const int* __restrict__ goffb, const int* __restrict__ blist,
    float* __restrict__ u_pre)
{
  int g = blockIdx.x, t = threadIdx.x;
  int a0 = goffa[g], a1 = goffa[g+1];
  float sA = 0.f;
  for (int i = a0; i < a1; ++i) sA += bf2f(Gh[(size_t)alist[i]*DD + t]);
  int b0 = goffb[g], b1 = goffb[g+1];
  float sB = 0.f;
  for (int i = b0; i < b1; ++i) sB += bf2f(He[(size_t)blist[i]*DD + t]);
  float cA = (float)max(a1 - a0, 1);
  float cB = (float)max(b1 - b0, 1);
  u_pre[(size_t)g*DD + t] = sA/cA + sB/cB + bf2f(Iu[(size_t)g*DD + t]);
}

__global__ void k_ustats(const float* __restrict__ u_pre, float* usum, float* usumsq){
  int t = threadIdx.x;
  float s = 0.f, s2 = 0.f;
  for (int g = blockIdx.x; g < NG; g += gridDim.x){
    float v = u_pre[(size_t)g*DD + t];
    s += v; s2 += v*v;
  }
  atomicAdd(&usum[t], s);
  atomicAdd(&usumsq[t], s2);
}

// ---------------- BN finalize + normalize/ELU ----------------
__global__ void k_bnfin(const float* __restrict__ sums, const float* __restrict__ sumsq,
                        float* __restrict__ mr){
  int o = blockIdx.x, t = threadIdx.x;
  float n = (o==0) ? (float)NA : (o==1) ? (float)NB : (float)NG;
  float m = sums[o*DD+t]/n;
  float v = sumsq[o*DD+t]/n - m*m;
  mr[o*2*DD + t]      = m;
  mr[o*2*DD + DD + t] = rsqrtf(fmaxf(v, 0.f) + EPS_BN);
}

__global__ __launch_bounds__(256) void k_norm(
    float* __restrict__ buf, size_t nrows,
    const float* __restrict__ mr, const float* __restrict__ gamma,
    const float* __restrict__ beta)
{
  __shared__ float sm[DD], sr[DD], sg[DD], sb[DD];
  int t = threadIdx.x;
  sm[t] = mr[t]; sr[t] = mr[DD+t]; sg[t] = gamma[t]; sb[t] = beta[t];
  __syncthreads();
  size_t total = nrows*(DD/4);
  for (size_t i = blockIdx.x*(size_t)blockDim.x + t; i < total;
       i += (size_t)gridDim.x*blockDim.x){
    int c = ((int)(i & 63))*4;
    float4 v = ((float4*)buf)[i];
    float z0 = (v.x - sm[c+0])*sr[c+0]*sg[c+0] + sb[c+0];
    float z1 = (v.y - sm[c+1])*sr[c+1]*sg[c+1] + sb[c+1];
    float z2 = (v.z - sm[c+2])*sr[c+2]*sg[c+2] + sb[c+2];
    float z3 = (v.w - sm[c+3])*sr[c+3]*sg[c+3] + sb[c+3];
    v.x = z0 > 0.f ? z0 : expm1f(z0);
    v.y = z1 > 0.f ? z1 : expm1f(z1);
    v.z = z2 > 0.f ? z2 : expm1f(z2);
    v.w = z3 > 0.f ? z3 : expm1f(z3);
    ((float4*)buf)[i] = v;
  }
}

// ================================ launcher =================================
extern "C" void kernel_launch(void* const* d_in, const int* in_sizes, int n_in,
                              void* d_out, int out_size, void* d_ws, size_t ws_size,
                              hipStream_t stream)
{
  (void)in_sizes; (void)n_in; (void)out_size;
  const float* h   = (const float*)d_in[0];
  const float* e   = (const float*)d_in[1];
  const float* u   = (const float*)d_in[2];
  const float* snn = (const float*)d_in[3];
  const float* sne = (const float*)d_in[4];
  const float* W   = (const float*)d_in[5];
  const float* b   = (const float*)d_in[6];
  const float* gamma = (const float*)d_in[7];
  const float* beta  = (const float*)d_in[8];
  const int* ba  = (const int*)d_in[9];
  const int* a2g = (const int*)d_in[10];
  const int* b2g = (const int*)d_in[11];

  float* outp  = (float*)d_out;
  float* h_pre = outp;
  float* e_pre = outp + (size_t)NA*DD;
  float* u_pre = outp + (size_t)(NA+NB)*DD;

  char* ws = (char*)d_ws;
  size_t off = 0;
  auto alloc = [&](size_t bytes)->char* {
    char* p = ws + off;
    off += (bytes + 255) & ~(size_t)255;
    return p;
  };
  unsigned short* Wbf = (unsigned short*)alloc((size_t)9*DD*DD*2);
  unsigned short* Yh  = (unsigned short*)alloc((size_t)4*NA*DD*2);
  unsigned short* Ye  = (unsigned short*)alloc((size_t)2*NB*DD*2);
  unsigned short* Yu  = (unsigned short*)alloc((size_t)3*NG*DD*2);
  unsigned short* Sg  = (unsigned short*)alloc((size_t)NB*DD*2);
  int* aoff  = (int*)alloc((size_t)(NA+1)*4);
  int* goffa = (int*)alloc((size_t)(NG+1)*4);
  int* goffb = (int*)alloc((size_t)(NG+1)*4);
  int* alist = (int*)alloc((size_t)NA*4);
  int* blist = (int*)alloc((size_t)NB*4);
  int* incb  = (int*)alloc((size_t)2*NB*4);
  int* inco  = (int*)alloc((size_t)2*NB*4);
  int* part  = (int*)alloc(1024);
  float* mr  = (float*)alloc((size_t)3*2*DD*4);
  char* zz   = ws + off;                      // ---- zero zone start ----
  int* deg      = (int*)alloc((size_t)NA*4);
  int* cur_atom = (int*)alloc((size_t)NA*4);
  int* cnta  = (int*)alloc((size_t)NG*4);
  int* cntb  = (int*)alloc((size_t)NG*4);
  int* cura  = (int*)alloc((size_t)NG*4);
  int* curb  = (int*)alloc((size_t)NG*4);
  float* sums  = (float*)alloc((size_t)3*DD*4);
  float* sumsq = (float*)alloc((size_t)3*DD*4);
  size_t zbytes = (size_t)((ws + off) - zz);

  if (ws_size < off) return;

  unsigned short* Ah = Yh;
  unsigned short* Dh = Yh + (size_t)1*NA*DD;
  unsigned short* Eh = Yh + (size_t)2*NA*DD;
  unsigned short* Gh = Yh + (size_t)3*NA*DD;
  unsigned short* Be = Ye;
  unsigned short* He = Ye + (size_t)NB*DD;
  unsigned short* Cu = Yu;
  unsigned short* Fu = Yu + (size_t)1*NG*DD;
  unsigned short* Iu = Yu + (size_t)2*NG*DD;

  k_zero<<<256, 256, 0, stream>>>((int4*)zz, zbytes/16);
  k_wconv<<<288, 256, 0, stream>>>(W, Wbf, 9*DD*DD/4);

  k_gemm4<<<(NA+127)/128, 512, 0, stream>>>(h, NA, Wbf, b, Yh, 0,3,4,6, 4);
  k_gemm4<<<(NB+127)/128, 512, 0, stream>>>(e, NB, Wbf, b, Ye, 1,7,0,0, 2);
  k_gemm4<<<(NG+127)/128, 512, 0, stream>>>(u, NG, Wbf, b, Yu, 2,5,8,0, 3);

  k_hist<<<1024, 256, 0, stream>>>(ba, b2g, a2g, deg, cntb, cnta);

  k_scan_partials<<<98, 256, 0, stream>>>(deg, NA, part);
  k_scan_small<<<1, 64, 0, stream>>>(part, 98);
  k_scan_final<<<98, 256, 0, stream>>>(deg, NA, part, aoff);
  k_scan_partials<<<5, 256, 0, stream>>>(cnta, NG, part);
  k_scan_small<<<1, 64, 0, stream>>>(part, 5);
  k_scan_final<<<5, 256, 0, stream>>>(cnta, NG, part, goffa);
  k_scan_partials<<<5, 256, 0, stream>>>(cntb, NG, part);
  k_scan_small<<<1, 64, 0, stream>>>(part, 5);
  k_scan_final<<<5, 256, 0, stream>>>(cntb, NG, part, goffb);

  k_scatter_atoms<<<512, 256, 0, stream>>>(a2g, goffa, cura, alist);
  k_scatter_bonds<<<512, 256, 0, stream>>>(ba, b2g, goffb, curb, blist,
                                           aoff, cur_atom, incb, inco);

  k_bond<<<2048, 256, 0, stream>>>(Ah, Be, Cu, ba, b2g, sne, Sg, e_pre,
                                   sums + DD, sumsq + DD);
  k_atom<<<2048, 256, 0, stream>>>(Dh, Eh, Fu, Sg, aoff, incb, inco, a2g, snn,
                                   h_pre, sums + 0, sumsq + 0);
  k_graph<<<NG, 256, 0, stream>>>(Gh, He, Iu, goffa, alist, goffb, blist, u_pre);
  k_ustats<<<40, 256, 0, stream>>>(u_pre, sums + 2*DD, sumsq + 2*DD);

  k_bnfin<<<3, 256, 0, stream>>>(sums, sumsq, mr);

  k_norm<<<2048, 256, 0, stream>>>(h_pre, (size_t)NA, mr + 0,      gamma + 0,    beta + 0);
  k_norm<<<2048, 256, 0, stream>>>(e_pre, (size_t)NB, mr + 2*DD,   gamma + DD,   beta + DD);
  k_norm<<<64,   256, 0, stream>>>(u_pre, (size_t)NG, mr + 4*DD,   gamma + 2*DD, beta + 2*DD);
}